// Round 19
// baseline (171.073 us; speedup 1.0000x reference)
//
#include <hip/hip_runtime.h>

typedef __bf16 bf16;
typedef __attribute__((ext_vector_type(8))) bf16 bf16x8;
typedef __attribute__((ext_vector_type(4))) float f32x4;

// async global->LDS (LDS dest is wave-uniform base + lane*16)
#define GLDS16(g, l) __builtin_amdgcn_global_load_lds( \
    (const __attribute__((address_space(1))) void*)(g), \
    (__attribute__((address_space(3))) void*)(l), 16, 0, 0)

// log2(e)/sqrt(128): folded into q at the QKV epilogue so softmax uses exp2 directly
#define QSCALE 0.12751744f

static __device__ __forceinline__ f32x4 MFMA(bf16x8 a, bf16x8 b, f32x4 c) {
    return __builtin_amdgcn_mfma_f32_16x16x32_bf16(a, b, c, 0, 0, 0);
}
static __device__ __forceinline__ unsigned pack2(float a, float b) {
    unsigned short lo = __builtin_bit_cast(unsigned short, (bf16)a);
    unsigned short hi = __builtin_bit_cast(unsigned short, (bf16)b);
    return (unsigned)lo | ((unsigned)hi << 16);
}

// ---------------------------------------------------------------- convert f32->bf16
__global__ __launch_bounds__(256) void convert_kernel(
    const float* __restrict__ x, const float* __restrict__ wq,
    const float* __restrict__ wk, const float* __restrict__ wv,
    const float* __restrict__ wp,
    bf16* __restrict__ xb, bf16* __restrict__ wqkvb, bf16* __restrict__ wpb)
{
    int bid = blockIdx.x;
    const float* src; bf16* dst; int base;
    if (bid < 4096)      { src = x;  dst = xb;              base = bid * 2048; }
    else if (bid < 4608) { src = wq; dst = wqkvb;           base = (bid - 4096) * 2048; }
    else if (bid < 5120) { src = wk; dst = wqkvb + 1048576; base = (bid - 4608) * 2048; }
    else if (bid < 5632) { src = wv; dst = wqkvb + 2097152; base = (bid - 5120) * 2048; }
    else                 { src = wp; dst = wpb;             base = (bid - 5632) * 2048; }
    int i = base + threadIdx.x * 8;
    const f32x4* s4 = (const f32x4*)(src + i);
    f32x4 a = s4[0], c = s4[1];
    bf16x8 v;
    #pragma unroll
    for (int e = 0; e < 4; ++e) { v[e] = (bf16)a[e]; v[e + 4] = (bf16)c[e]; }
    *(bf16x8*)(dst + i) = v;
}

// ---------------------------------------------------------------- 128^2 BK=64 GEMM
// R17 champion (measured best across 12 variants). BM=BN=128, BK=64, 4 waves,
// per-wave C = 64x64. LDS 64 KiB -> 2 blocks/CU. Stage-first, ONE barrier/iter.
// Chunk-swizzle (chunk ^= row&7) on global source + ds_read (0 conflicts).
// MODE 0: QKV epilogue (q scaled, k, v transposed per head); MODE 1: f32+bias.
template <int MODE, int NTN>
__global__ __launch_bounds__(256, 2) void gemm2(
    const bf16* __restrict__ A, const bf16* __restrict__ B,
    const float* __restrict__ bias0, const float* __restrict__ bias1,
    const float* __restrict__ bias2,
    bf16* __restrict__ q_out, bf16* __restrict__ k_out, bf16* __restrict__ vt_out,
    float* __restrict__ f_out)
{
    constexpr int K = 1024;
    constexpr int NT = K / 64;
    constexpr int NWG = 64 * NTN;
    const int tid = threadIdx.x;
    const int lane = tid & 63;
    const int wid = tid >> 6;
    const int wr = wid >> 1, wc = wid & 1;
    const int l15 = lane & 15, l4 = lane >> 4, l7 = lane & 7;

    const int g = blockIdx.x;
    const int lin = (g & 7) * (NWG / 8) + (g >> 3);
    const int m0 = (lin / NTN) * 128, n0 = (lin % NTN) * 128;

    __shared__ __align__(16) bf16 lds[2][2][8192];

    const int rr = tid >> 3, pc = tid & 7;
    auto stage = [&](int buf, int t) {
        #pragma unroll
        for (int c = 0; c < 4; ++c) {
            int row = c * 32 + rr;
            int lc = pc ^ (row & 7);
            GLDS16(A + (size_t)(m0 + row) * K + t * 64 + lc * 8,
                   &lds[buf][0][c * 2048 + tid * 8]);
        }
        #pragma unroll
        for (int c = 0; c < 4; ++c) {
            int row = c * 32 + rr;
            int lc = pc ^ (row & 7);
            GLDS16(B + (size_t)(n0 + row) * K + t * 64 + lc * 8,
                   &lds[buf][1][c * 2048 + tid * 8]);
        }
    };

    const int arow = wr * 64 + l15;
    const int brow = wc * 64 + l15;
    #define RA(buf, f, kk) (*(const bf16x8*)((const char*)lds[buf][0] + \
        (arow + (f) * 16) * 128 + ((((kk) * 4 + l4) ^ l7) * 16)))
    #define RB(buf, j, kk) (*(const bf16x8*)((const char*)lds[buf][1] + \
        (brow + (j) * 16) * 128 + ((((kk) * 4 + l4) ^ l7) * 16)))

    f32x4 acc[4][4];
    #pragma unroll
    for (int f = 0; f < 4; ++f)
        #pragma unroll
        for (int j = 0; j < 4; ++j)
            #pragma unroll
            for (int e = 0; e < 4; ++e) acc[f][j][e] = 0.f;

    stage(0, 0);
    __syncthreads();

    for (int t = 0; t < NT; ++t) {
        const int buf = t & 1;
        if (t + 1 < NT) stage(buf ^ 1, t + 1);
        bf16x8 af[4][2], bfr[4][2];
        #pragma unroll
        for (int f = 0; f < 4; ++f) { af[f][0] = RA(buf, f, 0); af[f][1] = RA(buf, f, 1); }
        #pragma unroll
        for (int j = 0; j < 4; ++j) { bfr[j][0] = RB(buf, j, 0); bfr[j][1] = RB(buf, j, 1); }
        #pragma unroll
        for (int f = 0; f < 4; ++f)
            #pragma unroll
            for (int j = 0; j < 4; ++j) {
                acc[f][j] = MFMA(af[f][0], bfr[j][0], acc[f][j]);
                acc[f][j] = MFMA(af[f][1], bfr[j][1], acc[f][j]);
            }
        __syncthreads();
    }
    #undef RA
    #undef RB

    // epilogue: C/D layout col = lane&15, row = (lane>>4)*4 + reg  [m89-verified]
    #pragma unroll
    for (int f = 0; f < 4; ++f) {
        #pragma unroll
        for (int j = 0; j < 4; ++j) {
            #pragma unroll
            for (int r = 0; r < 4; ++r) {
                int m = m0 + wr * 64 + f * 16 + l4 * 4 + r;
                int n = n0 + wc * 64 + j * 16 + l15;
                float v = acc[f][j][r];
                if (MODE == 0) {
                    if (n0 < 1024) {
                        q_out[m * 1024 + n] = (bf16)((v + bias0[n]) * QSCALE);
                    } else if (n0 < 2048) {
                        int nn = n - 1024;
                        k_out[m * 1024 + nn] = (bf16)(v + bias1[nn]);
                    } else {
                        int nn = n - 2048;
                        int hl = nn >> 7, d = nn & 127;
                        int bb = m >> 10, tt = m & 1023;
                        vt_out[((bb * 8 + hl) * 128 + d) * 1024 + tt] = (bf16)(v + bias2[nn]);
                    }
                } else {
                    f_out[m * 1024 + n] = v + bias0[n];
                }
            }
        }
    }
}

// ---------------------------------------------------------------- flash attention v6
// v6 = R18 v5 (swapped QK^T, packed P) with QBLK=256: grid 256 = 8*8*(T/256) =
// exactly 1 block/CU (tail-free); 8 waves (512 thr) x 32 q-rows. Same 8
// waves/CU as before, but each CU stages HALF the K/V bytes (one KV pass, not
// two). LDS 96 KiB: K dbuf @0/16384, V dbuf @32768/49152, P @65536 (8x4 KiB).
__global__ __launch_bounds__(512, 2) void attn_kernel(
    const bf16* __restrict__ qb, const bf16* __restrict__ kb,
    const bf16* __restrict__ vtb, const int* __restrict__ mask,
    bf16* __restrict__ yb)
{
    const int tid = threadIdx.x;
    const int lane = tid & 63;
    const int wid = tid >> 6;          // 0..7
    const int g = blockIdx.x;
    const int orig = (g & 7) * 32 + (g >> 3);   // bijective XCD swizzle (256 = 8*32)
    const int bh = orig >> 2;
    const int qt = orig & 3;
    const int b = bh >> 3;
    const int h = bh & 7;
    const int m0 = b * 1024 + qt * 256;
    const int l15 = lane & 15, l4 = lane >> 4;

    __shared__ __align__(16) char smem[98304];
    // K buf: smem + buf*16384          [64 t'][128 d] swizzled
    // V buf: smem + 32768 + buf*16384  [128 d][64 t'] swizzled (V^T)
    // P:     smem + 65536 + wid*4096   per-wave [32 q][64 k] packed/swizzled

    auto stageKV = [&](int bufKV, int kt) {
        char* Kb = smem + bufKV * 16384;
        char* Vb = smem + 32768 + bufKV * 16384;
        // K: 64 rows x 256B; 512 thr x 2 calls x 16B
        #pragma unroll
        for (int n = 0; n < 2; ++n)
            GLDS16(kb + (b * 1024 + kt + n * 32 + (tid >> 4)) * 1024 + h * 128 +
                       (((tid & 15) ^ ((tid >> 4) & 7)) * 8),
                   Kb + n * 8192 + tid * 16);
        // V^T: 128 rows x 128B; 512 thr x 2 calls x 16B
        #pragma unroll
        for (int n = 0; n < 2; ++n)
            GLDS16(vtb + (bh * 128 + n * 64 + (tid >> 3)) * 1024 + kt +
                       (((tid & 7) ^ ((tid >> 3) & 7)) * 8),
                   Vb + n * 8192 + tid * 16);
    };

    bf16x8 qf[2][4];
    #pragma unroll
    for (int i = 0; i < 2; ++i)
        #pragma unroll
        for (int kc = 0; kc < 4; ++kc)
            qf[i][kc] = *(const bf16x8*)(qb +
                (m0 + wid * 32 + i * 16 + l15) * 1024 + h * 128 + kc * 32 + l4 * 8);

    f32x4 o[2][8];
    #pragma unroll
    for (int i = 0; i < 2; ++i)
        #pragma unroll
        for (int jd = 0; jd < 8; ++jd)
            #pragma unroll
            for (int e = 0; e < 4; ++e) o[i][jd][e] = 0.f;
    float l_run[2] = {0.f, 0.f};       // per-lane, q = i*16 + l15

    stageKV(0, 0);
    __syncthreads();

    for (int t = 0; t < 16; ++t) {
        const int buf = t & 1;
        const int kt = t * 64;
        if (t + 1 < 16) stageKV(buf ^ 1, kt + 64);   // issue next K/V FIRST

        int4 mv4[4];
        #pragma unroll
        for (int j = 0; j < 4; ++j)
            mv4[j] = *(const int4*)(mask + b * 1024 + kt + j * 16 + l4 * 4);

        const char* Ks = smem + buf * 16384;
        const char* Vs = smem + 32768 + buf * 16384;

        // S^T = K Q^T (swapped): lane holds S[q=i*16+l15][k=j*16+l4*4+r]
        f32x4 s[2][4];
        #pragma unroll
        for (int i = 0; i < 2; ++i)
            #pragma unroll
            for (int j = 0; j < 4; ++j)
                #pragma unroll
                for (int e = 0; e < 4; ++e) s[i][j][e] = 0.f;
        #pragma unroll
        for (int kc = 0; kc < 4; ++kc) {
            bf16x8 kf[4];
            #pragma unroll
            for (int j = 0; j < 4; ++j)
                kf[j] = *(const bf16x8*)(Ks + (j * 16 + l15) * 256 +
                    (((kc * 4 + l4) ^ (lane & 7)) * 16));
            __builtin_amdgcn_s_setprio(1);
            #pragma unroll
            for (int i = 0; i < 2; ++i)
                #pragma unroll
                for (int j = 0; j < 4; ++j)
                    s[i][j] = MFMA(kf[j], qf[i][kc], s[i][j]);
            __builtin_amdgcn_s_setprio(0);
        }

        // un-subtracted softmax: p = exp2(s) (mask -> 0); per-lane partials
        #pragma unroll
        for (int i = 0; i < 2; ++i)
            #pragma unroll
            for (int j = 0; j < 4; ++j) {
                s[i][j][0] = mv4[j].x ? __builtin_amdgcn_exp2f(s[i][j][0]) : 0.f;
                s[i][j][1] = mv4[j].y ? __builtin_amdgcn_exp2f(s[i][j][1]) : 0.f;
                s[i][j][2] = mv4[j].z ? __builtin_amdgcn_exp2f(s[i][j][2]) : 0.f;
                s[i][j][3] = mv4[j].w ? __builtin_amdgcn_exp2f(s[i][j][3]) : 0.f;
                l_run[i] += s[i][j][0] + s[i][j][1] + s[i][j][2] + s[i][j][3];
            }

        // P -> per-wave LDS [32 q][32 u32], packed pairs, swizzled chunk^(q&7)
        #pragma unroll
        for (int i = 0; i < 2; ++i) {
            char* pw = smem + 65536 + wid * 4096 + (i * 16 + l15) * 128;
            #pragma unroll
            for (int j = 0; j < 4; ++j) {
                char* pcq = pw + (((j * 2 + (l4 >> 1)) ^ (l15 & 7)) * 16) +
                            ((l4 & 1) * 2) * 4;
                *(unsigned*)(pcq)     = pack2(s[i][j][0], s[i][j][1]);
                *(unsigned*)(pcq + 4) = pack2(s[i][j][2], s[i][j][3]);
            }
        }

        // O += P V
        #pragma unroll
        for (int k2 = 0; k2 < 2; ++k2) {
            bf16x8 pa[2];
            #pragma unroll
            for (int i = 0; i < 2; ++i)
                pa[i] = *(const bf16x8*)(smem + 65536 + wid * 4096 +
                    (i * 16 + l15) * 128 + (((k2 * 4 + l4) ^ (l15 & 7)) * 16));
            __builtin_amdgcn_s_setprio(1);
            #pragma unroll
            for (int jd = 0; jd < 8; ++jd) {
                bf16x8 vf = *(const bf16x8*)(Vs + (jd * 16 + l15) * 128 +
                    (((k2 * 4 + l4) ^ (l15 & 7)) * 16));
                o[0][jd] = MFMA(pa[0], vf, o[0][jd]);
                o[1][jd] = MFMA(pa[1], vf, o[1][jd]);
            }
            __builtin_amdgcn_s_setprio(0);
        }
        __syncthreads();
    }

    // epilogue: reduce l over l4 groups, transpose to O-layout q via LDS scratch
    #pragma unroll
    for (int i = 0; i < 2; ++i) {
        l_run[i] += __shfl_xor(l_run[i], 16);
        l_run[i] += __shfl_xor(l_run[i], 32);
    }
    float* sc = (float*)(smem + 65536 + wid * 4096);   // reuse dead P region
    if (l4 == 0) { sc[l15] = l_run[0]; sc[16 + l15] = l_run[1]; }
    __syncthreads();
    #pragma unroll
    for (int i = 0; i < 2; ++i) {
        float inv[4];
        #pragma unroll
        for (int r = 0; r < 4; ++r)
            inv[r] = 1.0f / fmaxf(sc[i * 16 + l4 * 4 + r], 1e-30f);
        #pragma unroll
        for (int jd = 0; jd < 8; ++jd)
            #pragma unroll
            for (int r = 0; r < 4; ++r)
                yb[(m0 + wid * 32 + i * 16 + l4 * 4 + r) * 1024 +
                   h * 128 + jd * 16 + l15] = (bf16)(o[i][jd][r] * inv[r]);
    }
}

// ---------------------------------------------------------------- launch
extern "C" void kernel_launch(void* const* d_in, const int* in_sizes, int n_in,
                              void* d_out, int out_size, void* d_ws, size_t ws_size,
                              hipStream_t stream)
{
    (void)in_sizes; (void)n_in; (void)out_size; (void)ws_size;
    const float* x  = (const float*)d_in[0];
    const int* mask = (const int*)d_in[1];
    const float* Wq = (const float*)d_in[2];
    const float* bq = (const float*)d_in[3];
    const float* Wk = (const float*)d_in[4];
    const float* bk = (const float*)d_in[5];
    const float* Wv = (const float*)d_in[6];
    const float* bv = (const float*)d_in[7];
    const float* Wp = (const float*)d_in[8];
    const float* bp = (const float*)d_in[9];
    float* out = (float*)d_out;

    char* ws = (char*)d_ws;
    bf16* xb    = (bf16*)(ws);                      // 16 MB  x bf16 (8192 x 1024)
    bf16* wqkvb = (bf16*)(ws + (16u << 20));        //  6 MB  [Wq;Wk;Wv]
    bf16* wpb   = (bf16*)(ws + (22u << 20));        //  2 MB  Wp
    bf16* qbuf  = (bf16*)(ws + (24u << 20));        // 16 MB  q (scaled)
    bf16* kbuf  = (bf16*)(ws + (40u << 20));        // 16 MB  k
    bf16* vtb   = (bf16*)(ws + (56u << 20));        // 16 MB  v^T per (b,h)
    bf16* ybuf  = (bf16*)(ws + (72u << 20));        // 16 MB  attention out

    convert_kernel<<<6144, 256, 0, stream>>>(x, Wq, Wk, Wv, Wp, xb, wqkvb, wpb);
    gemm2<0, 24><<<1536, 256, 0, stream>>>(xb, wqkvb, bq, bk, bv,
                                           qbuf, kbuf, vtb, nullptr);
    attn_kernel<<<256, 512, 0, stream>>>(qbuf, kbuf, vtb, mask, ybuf);
    gemm2<1, 8><<<512, 256, 0, stream>>>(ybuf, wpb, bp, nullptr, nullptr,
                                         nullptr, nullptr, nullptr, out);
}

// Round 20
// 170.249 us; speedup vs baseline: 1.0048x; 1.0048x over previous
//
#include <hip/hip_runtime.h>

typedef __bf16 bf16;
typedef __attribute__((ext_vector_type(8))) bf16 bf16x8;
typedef __attribute__((ext_vector_type(4))) float f32x4;

// async global->LDS (LDS dest is wave-uniform base + lane*16)
#define GLDS16(g, l) __builtin_amdgcn_global_load_lds( \
    (const __attribute__((address_space(1))) void*)(g), \
    (__attribute__((address_space(3))) void*)(l), 16, 0, 0)

// log2(e)/sqrt(128): folded into q at the QKV epilogue so softmax uses exp2 directly
#define QSCALE 0.12751744f

static __device__ __forceinline__ f32x4 MFMA(bf16x8 a, bf16x8 b, f32x4 c) {
    return __builtin_amdgcn_mfma_f32_16x16x32_bf16(a, b, c, 0, 0, 0);
}
static __device__ __forceinline__ unsigned pack2(float a, float b) {
    unsigned short lo = __builtin_bit_cast(unsigned short, (bf16)a);
    unsigned short hi = __builtin_bit_cast(unsigned short, (bf16)b);
    return (unsigned)lo | ((unsigned)hi << 16);
}

// ---------------------------------------------------------------- convert f32->bf16
__global__ __launch_bounds__(256) void convert_kernel(
    const float* __restrict__ x, const float* __restrict__ wq,
    const float* __restrict__ wk, const float* __restrict__ wv,
    const float* __restrict__ wp,
    bf16* __restrict__ xb, bf16* __restrict__ wqkvb, bf16* __restrict__ wpb)
{
    int bid = blockIdx.x;
    const float* src; bf16* dst; int base;
    if (bid < 4096)      { src = x;  dst = xb;              base = bid * 2048; }
    else if (bid < 4608) { src = wq; dst = wqkvb;           base = (bid - 4096) * 2048; }
    else if (bid < 5120) { src = wk; dst = wqkvb + 1048576; base = (bid - 4608) * 2048; }
    else if (bid < 5632) { src = wv; dst = wqkvb + 2097152; base = (bid - 5120) * 2048; }
    else                 { src = wp; dst = wpb;             base = (bid - 5632) * 2048; }
    int i = base + threadIdx.x * 8;
    const f32x4* s4 = (const f32x4*)(src + i);
    f32x4 a = s4[0], c = s4[1];
    bf16x8 v;
    #pragma unroll
    for (int e = 0; e < 4; ++e) { v[e] = (bf16)a[e]; v[e + 4] = (bf16)c[e]; }
    *(bf16x8*)(dst + i) = v;
}

// ---------------------------------------------------------------- 128^2 BK=64 GEMM
// R10 champion EXACTLY (with setprio: within-session A/B R10 91.5-92.5 us vs
// R17-19 95.6-97.4 us without -- setprio is positive here, 2 co-resident
// blocks give the scheduler role diversity). BM=BN=128, BK=64, 4 waves,
// per-wave C = 64x64. LDS 64 KiB -> 2 blocks/CU. Stage-first, ONE barrier/iter.
// Chunk-swizzle (chunk ^= row&7) on global source + ds_read (0 conflicts).
// MODE 0: QKV epilogue (q scaled, k, v transposed per head); MODE 1: f32+bias.
template <int MODE, int NTN>
__global__ __launch_bounds__(256, 2) void gemm2(
    const bf16* __restrict__ A, const bf16* __restrict__ B,
    const float* __restrict__ bias0, const float* __restrict__ bias1,
    const float* __restrict__ bias2,
    bf16* __restrict__ q_out, bf16* __restrict__ k_out, bf16* __restrict__ vt_out,
    float* __restrict__ f_out)
{
    constexpr int K = 1024;
    constexpr int NT = K / 64;
    constexpr int NWG = 64 * NTN;
    const int tid = threadIdx.x;
    const int lane = tid & 63;
    const int wid = tid >> 6;
    const int wr = wid >> 1, wc = wid & 1;
    const int l15 = lane & 15, l4 = lane >> 4, l7 = lane & 7;

    const int g = blockIdx.x;
    const int lin = (g & 7) * (NWG / 8) + (g >> 3);
    const int m0 = (lin / NTN) * 128, n0 = (lin % NTN) * 128;

    __shared__ __align__(16) bf16 lds[2][2][8192];

    const int rr = tid >> 3, pc = tid & 7;
    auto stage = [&](int buf, int t) {
        #pragma unroll
        for (int c = 0; c < 4; ++c) {
            int row = c * 32 + rr;
            int lc = pc ^ (row & 7);
            GLDS16(A + (size_t)(m0 + row) * K + t * 64 + lc * 8,
                   &lds[buf][0][c * 2048 + tid * 8]);
        }
        #pragma unroll
        for (int c = 0; c < 4; ++c) {
            int row = c * 32 + rr;
            int lc = pc ^ (row & 7);
            GLDS16(B + (size_t)(n0 + row) * K + t * 64 + lc * 8,
                   &lds[buf][1][c * 2048 + tid * 8]);
        }
    };

    const int arow = wr * 64 + l15;
    const int brow = wc * 64 + l15;
    #define RA(buf, f, kk) (*(const bf16x8*)((const char*)lds[buf][0] + \
        (arow + (f) * 16) * 128 + ((((kk) * 4 + l4) ^ l7) * 16)))
    #define RB(buf, j, kk) (*(const bf16x8*)((const char*)lds[buf][1] + \
        (brow + (j) * 16) * 128 + ((((kk) * 4 + l4) ^ l7) * 16)))

    f32x4 acc[4][4];
    #pragma unroll
    for (int f = 0; f < 4; ++f)
        #pragma unroll
        for (int j = 0; j < 4; ++j)
            #pragma unroll
            for (int e = 0; e < 4; ++e) acc[f][j][e] = 0.f;

    stage(0, 0);
    __syncthreads();

    for (int t = 0; t < NT; ++t) {
        const int buf = t & 1;
        if (t + 1 < NT) stage(buf ^ 1, t + 1);   // issue next-tile loads FIRST
        bf16x8 af[4][2], bfr[4][2];
        #pragma unroll
        for (int f = 0; f < 4; ++f) { af[f][0] = RA(buf, f, 0); af[f][1] = RA(buf, f, 1); }
        #pragma unroll
        for (int j = 0; j < 4; ++j) { bfr[j][0] = RB(buf, j, 0); bfr[j][1] = RB(buf, j, 1); }
        __builtin_amdgcn_s_setprio(1);
        #pragma unroll
        for (int f = 0; f < 4; ++f)
            #pragma unroll
            for (int j = 0; j < 4; ++j) {
                acc[f][j] = MFMA(af[f][0], bfr[j][0], acc[f][j]);
                acc[f][j] = MFMA(af[f][1], bfr[j][1], acc[f][j]);
            }
        __builtin_amdgcn_s_setprio(0);
        __syncthreads();   // drains vmcnt (stage had the whole phase to land)
    }
    #undef RA
    #undef RB

    // epilogue: C/D layout col = lane&15, row = (lane>>4)*4 + reg  [m89-verified]
    #pragma unroll
    for (int f = 0; f < 4; ++f) {
        #pragma unroll
        for (int j = 0; j < 4; ++j) {
            #pragma unroll
            for (int r = 0; r < 4; ++r) {
                int m = m0 + wr * 64 + f * 16 + l4 * 4 + r;
                int n = n0 + wc * 64 + j * 16 + l15;
                float v = acc[f][j][r];
                if (MODE == 0) {
                    if (n0 < 1024) {
                        q_out[m * 1024 + n] = (bf16)((v + bias0[n]) * QSCALE);
                    } else if (n0 < 2048) {
                        int nn = n - 1024;
                        k_out[m * 1024 + nn] = (bf16)(v + bias1[nn]);
                    } else {
                        int nn = n - 2048;
                        int hl = nn >> 7, d = nn & 127;
                        int bb = m >> 10, tt = m & 1023;
                        vt_out[((bb * 8 + hl) * 128 + d) * 1024 + tt] = (bf16)(v + bias2[nn]);
                    }
                } else {
                    f_out[m * 1024 + n] = v + bias0[n];
                }
            }
        }
    }
}

// ---------------------------------------------------------------- flash attention v5
// R18 champion attn: QBLK=128 (grid 512, 4 waves x 32 q-rows), swapped QK^T
// (mfma(K,Q)) with packed-u32 P writes (8 ds_write_b64 vs 32 ds_write_u16),
// un-subtracted softmax, dbuf single-barrier, setprio. LDS 80 KiB.
__global__ __launch_bounds__(256, 2) void attn_kernel(
    const bf16* __restrict__ qb, const bf16* __restrict__ kb,
    const bf16* __restrict__ vtb, const int* __restrict__ mask,
    bf16* __restrict__ yb)
{
    const int tid = threadIdx.x;
    const int lane = tid & 63;
    const int wid = tid >> 6;
    const int g = blockIdx.x;
    const int orig = (g & 7) * 64 + (g >> 3);   // bijective XCD swizzle (512 = 8*64)
    const int bh = orig >> 3;
    const int qt = orig & 7;
    const int b = bh >> 3;
    const int h = bh & 7;
    const int m0 = b * 1024 + qt * 128;
    const int l15 = lane & 15, l4 = lane >> 4;

    __shared__ __align__(16) char smem[81920];
    auto stageKV = [&](int bufKV, int kt) {
        char* Kb = smem + bufKV * 16384;
        char* Vb = smem + 32768 + bufKV * 16384;
        #pragma unroll
        for (int n = 0; n < 4; ++n)
            GLDS16(kb + (b * 1024 + kt + n * 16 + (tid >> 4)) * 1024 + h * 128 +
                       (((tid & 15) ^ ((tid >> 4) & 7)) * 8),
                   Kb + n * 4096 + tid * 16);
        #pragma unroll
        for (int n = 0; n < 4; ++n)
            GLDS16(vtb + (bh * 128 + n * 32 + (tid >> 3)) * 1024 + kt +
                       (((tid & 7) ^ ((tid >> 3) & 7)) * 8),
                   Vb + n * 4096 + tid * 16);
    };

    bf16x8 qf[2][4];
    #pragma unroll
    for (int i = 0; i < 2; ++i)
        #pragma unroll
        for (int kc = 0; kc < 4; ++kc)
            qf[i][kc] = *(const bf16x8*)(qb +
                (m0 + wid * 32 + i * 16 + l15) * 1024 + h * 128 + kc * 32 + l4 * 8);

    f32x4 o[2][8];
    #pragma unroll
    for (int i = 0; i < 2; ++i)
        #pragma unroll
        for (int jd = 0; jd < 8; ++jd)
            #pragma unroll
            for (int e = 0; e < 4; ++e) o[i][jd][e] = 0.f;
    float l_run[2] = {0.f, 0.f};       // per-lane, q = i*16 + l15

    stageKV(0, 0);
    __syncthreads();

    for (int t = 0; t < 16; ++t) {
        const int buf = t & 1;
        const int kt = t * 64;
        if (t + 1 < 16) stageKV(buf ^ 1, kt + 64);   // issue next K/V FIRST

        int4 mv4[4];
        #pragma unroll
        for (int j = 0; j < 4; ++j)
            mv4[j] = *(const int4*)(mask + b * 1024 + kt + j * 16 + l4 * 4);

        const char* Ks = smem + buf * 16384;
        const char* Vs = smem + 32768 + buf * 16384;

        // S^T = K Q^T (swapped): lane holds S[q=i*16+l15][k=j*16+l4*4+r]
        f32x4 s[2][4];
        #pragma unroll
        for (int i = 0; i < 2; ++i)
            #pragma unroll
            for (int j = 0; j < 4; ++j)
                #pragma unroll
                for (int e = 0; e < 4; ++e) s[i][j][e] = 0.f;
        #pragma unroll
        for (int kc = 0; kc < 4; ++kc) {
            bf16x8 kf[4];
            #pragma unroll
            for (int j = 0; j < 4; ++j)
                kf[j] = *(const bf16x8*)(Ks + (j * 16 + l15) * 256 +
                    (((kc * 4 + l4) ^ (lane & 7)) * 16));
            __builtin_amdgcn_s_setprio(1);
            #pragma unroll
            for (int i = 0; i < 2; ++i)
                #pragma unroll
                for (int j = 0; j < 4; ++j)
                    s[i][j] = MFMA(kf[j], qf[i][kc], s[i][j]);
            __builtin_amdgcn_s_setprio(0);
        }

        // un-subtracted softmax: p = exp2(s) (mask -> 0); per-lane partials
        #pragma unroll
        for (int i = 0; i < 2; ++i)
            #pragma unroll
            for (int j = 0; j < 4; ++j) {
                s[i][j][0] = mv4[j].x ? __builtin_amdgcn_exp2f(s[i][j][0]) : 0.f;
                s[i][j][1] = mv4[j].y ? __builtin_amdgcn_exp2f(s[i][j][1]) : 0.f;
                s[i][j][2] = mv4[j].z ? __builtin_amdgcn_exp2f(s[i][j][2]) : 0.f;
                s[i][j][3] = mv4[j].w ? __builtin_amdgcn_exp2f(s[i][j][3]) : 0.f;
                l_run[i] += s[i][j][0] + s[i][j][1] + s[i][j][2] + s[i][j][3];
            }

        // P -> per-wave LDS [32 q][32 u32], packed pairs, swizzled chunk^(q&7)
        #pragma unroll
        for (int i = 0; i < 2; ++i) {
            char* pw = smem + 65536 + wid * 4096 + (i * 16 + l15) * 128;
            #pragma unroll
            for (int j = 0; j < 4; ++j) {
                char* pcq = pw + (((j * 2 + (l4 >> 1)) ^ (l15 & 7)) * 16) +
                            ((l4 & 1) * 2) * 4;
                *(unsigned*)(pcq)     = pack2(s[i][j][0], s[i][j][1]);
                *(unsigned*)(pcq + 4) = pack2(s[i][j][2], s[i][j][3]);
            }
        }

        // O += P V
        #pragma unroll
        for (int k2 = 0; k2 < 2; ++k2) {
            bf16x8 pa[2];
            #pragma unroll
            for (int i = 0; i < 2; ++i)
                pa[i] = *(const bf16x8*)(smem + 65536 + wid * 4096 +
                    (i * 16 + l15) * 128 + (((k2 * 4 + l4) ^ (l15 & 7)) * 16));
            __builtin_amdgcn_s_setprio(1);
            #pragma unroll
            for (int jd = 0; jd < 8; ++jd) {
                bf16x8 vf = *(const bf16x8*)(Vs + (jd * 16 + l15) * 128 +
                    (((k2 * 4 + l4) ^ (l15 & 7)) * 16));
                o[0][jd] = MFMA(pa[0], vf, o[0][jd]);
                o[1][jd] = MFMA(pa[1], vf, o[1][jd]);
            }
            __builtin_amdgcn_s_setprio(0);
        }
        __syncthreads();
    }

    // epilogue: reduce l over l4 groups, transpose to O-layout q via LDS scratch
    #pragma unroll
    for (int i = 0; i < 2; ++i) {
        l_run[i] += __shfl_xor(l_run[i], 16);
        l_run[i] += __shfl_xor(l_run[i], 32);
    }
    float* sc = (float*)(smem + 65536 + wid * 4096);   // reuse dead P region
    if (l4 == 0) { sc[l15] = l_run[0]; sc[16 + l15] = l_run[1]; }
    __syncthreads();
    #pragma unroll
    for (int i = 0; i < 2; ++i) {
        float inv[4];
        #pragma unroll
        for (int r = 0; r < 4; ++r)
            inv[r] = 1.0f / fmaxf(sc[i * 16 + l4 * 4 + r], 1e-30f);
        #pragma unroll
        for (int jd = 0; jd < 8; ++jd)
            #pragma unroll
            for (int r = 0; r < 4; ++r)
                yb[(m0 + wid * 32 + i * 16 + l4 * 4 + r) * 1024 +
                   h * 128 + jd * 16 + l15] = (bf16)(o[i][jd][r] * inv[r]);
    }
}

// ---------------------------------------------------------------- launch
extern "C" void kernel_launch(void* const* d_in, const int* in_sizes, int n_in,
                              void* d_out, int out_size, void* d_ws, size_t ws_size,
                              hipStream_t stream)
{
    (void)in_sizes; (void)n_in; (void)out_size; (void)ws_size;
    const float* x  = (const float*)d_in[0];
    const int* mask = (const int*)d_in[1];
    const float* Wq = (const float*)d_in[2];
    const float* bq = (const float*)d_in[3];
    const float* Wk = (const float*)d_in[4];
    const float* bk = (const float*)d_in[5];
    const float* Wv = (const float*)d_in[6];
    const float* bv = (const float*)d_in[7];
    const float* Wp = (const float*)d_in[8];
    const float* bp = (const float*)d_in[9];
    float* out = (float*)d_out;

    char* ws = (char*)d_ws;
    bf16* xb    = (bf16*)(ws);                      // 16 MB  x bf16 (8192 x 1024)
    bf16* wqkvb = (bf16*)(ws + (16u << 20));        //  6 MB  [Wq;Wk;Wv]
    bf16* wpb   = (bf16*)(ws + (22u << 20));        //  2 MB  Wp
    bf16* qbuf  = (bf16*)(ws + (24u << 20));        // 16 MB  q (scaled)
    bf16* kbuf  = (bf16*)(ws + (40u << 20));        // 16 MB  k
    bf16* vtb   = (bf16*)(ws + (56u << 20));        // 16 MB  v^T per (b,h)
    bf16* ybuf  = (bf16*)(ws + (72u << 20));        // 16 MB  attention out

    convert_kernel<<<6144, 256, 0, stream>>>(x, Wq, Wk, Wv, Wp, xb, wqkvb, wpb);
    gemm2<0, 24><<<1536, 256, 0, stream>>>(xb, wqkvb, bq, bk, bv,
                                           qbuf, kbuf, vtb, nullptr);
    attn_kernel<<<512, 256, 0, stream>>>(qbuf, kbuf, vtb, mask, ybuf);
    gemm2<1, 8><<<512, 256, 0, stream>>>(ybuf, wpb, bp, nullptr, nullptr,
                                         nullptr, nullptr, nullptr, out);
}

// Round 21
// 170.057 us; speedup vs baseline: 1.0060x; 1.0011x over previous
//
#include <hip/hip_runtime.h>

typedef __bf16 bf16;
typedef __attribute__((ext_vector_type(8))) bf16 bf16x8;
typedef __attribute__((ext_vector_type(4))) float f32x4;

// async global->LDS (LDS dest is wave-uniform base + lane*16)
#define GLDS16(g, l) __builtin_amdgcn_global_load_lds( \
    (const __attribute__((address_space(1))) void*)(g), \
    (__attribute__((address_space(3))) void*)(l), 16, 0, 0)

// log2(e)/sqrt(128): folded into q at the QKV epilogue so softmax uses exp2 directly
#define QSCALE 0.12751744f

static __device__ __forceinline__ f32x4 MFMA(bf16x8 a, bf16x8 b, f32x4 c) {
    return __builtin_amdgcn_mfma_f32_16x16x32_bf16(a, b, c, 0, 0, 0);
}
static __device__ __forceinline__ unsigned pack2(float a, float b) {
    unsigned short lo = __builtin_bit_cast(unsigned short, (bf16)a);
    unsigned short hi = __builtin_bit_cast(unsigned short, (bf16)b);
    return (unsigned)lo | ((unsigned)hi << 16);
}

// ---------------------------------------------------------------- convert f32->bf16
__global__ __launch_bounds__(256) void convert_kernel(
    const float* __restrict__ x, const float* __restrict__ wq,
    const float* __restrict__ wk, const float* __restrict__ wv,
    const float* __restrict__ wp,
    bf16* __restrict__ xb, bf16* __restrict__ wqkvb, bf16* __restrict__ wpb)
{
    int bid = blockIdx.x;
    const float* src; bf16* dst; int base;
    if (bid < 4096)      { src = x;  dst = xb;              base = bid * 2048; }
    else if (bid < 4608) { src = wq; dst = wqkvb;           base = (bid - 4096) * 2048; }
    else if (bid < 5120) { src = wk; dst = wqkvb + 1048576; base = (bid - 4608) * 2048; }
    else if (bid < 5632) { src = wv; dst = wqkvb + 2097152; base = (bid - 5120) * 2048; }
    else                 { src = wp; dst = wpb;             base = (bid - 5632) * 2048; }
    int i = base + threadIdx.x * 8;
    const f32x4* s4 = (const f32x4*)(src + i);
    f32x4 a = s4[0], c = s4[1];
    bf16x8 v;
    #pragma unroll
    for (int e = 0; e < 4; ++e) { v[e] = (bf16)a[e]; v[e + 4] = (bf16)c[e]; }
    *(bf16x8*)(dst + i) = v;
}

// ---------------------------------------------------------------- 128^2 BK=64 GEMM
// R10/R20 champion structure. BM=BN=128, BK=64, 4 waves, per-wave C = 64x64.
// LDS 64 KiB -> 2 blocks/CU. Stage-first, ONE barrier/iter. Chunk-swizzle
// (chunk ^= row&7) on global source + ds_read (0 conflicts).
// PRIO: setprio around MFMA -- measured +4 us on QKV (3-round grid, role
// diversity) but suspected negative on proj (single-round, L2-hot staging):
// QKV instantiates PRIO=1, proj PRIO=0 (final cell of the A/B matrix).
// MODE 0: QKV epilogue (q scaled, k, v transposed per head); MODE 1: f32+bias.
template <int MODE, int NTN, int PRIO>
__global__ __launch_bounds__(256, 2) void gemm2(
    const bf16* __restrict__ A, const bf16* __restrict__ B,
    const float* __restrict__ bias0, const float* __restrict__ bias1,
    const float* __restrict__ bias2,
    bf16* __restrict__ q_out, bf16* __restrict__ k_out, bf16* __restrict__ vt_out,
    float* __restrict__ f_out)
{
    constexpr int K = 1024;
    constexpr int NT = K / 64;
    constexpr int NWG = 64 * NTN;
    const int tid = threadIdx.x;
    const int lane = tid & 63;
    const int wid = tid >> 6;
    const int wr = wid >> 1, wc = wid & 1;
    const int l15 = lane & 15, l4 = lane >> 4, l7 = lane & 7;

    const int g = blockIdx.x;
    const int lin = (g & 7) * (NWG / 8) + (g >> 3);
    const int m0 = (lin / NTN) * 128, n0 = (lin % NTN) * 128;

    __shared__ __align__(16) bf16 lds[2][2][8192];

    const int rr = tid >> 3, pc = tid & 7;
    auto stage = [&](int buf, int t) {
        #pragma unroll
        for (int c = 0; c < 4; ++c) {
            int row = c * 32 + rr;
            int lc = pc ^ (row & 7);
            GLDS16(A + (size_t)(m0 + row) * K + t * 64 + lc * 8,
                   &lds[buf][0][c * 2048 + tid * 8]);
        }
        #pragma unroll
        for (int c = 0; c < 4; ++c) {
            int row = c * 32 + rr;
            int lc = pc ^ (row & 7);
            GLDS16(B + (size_t)(n0 + row) * K + t * 64 + lc * 8,
                   &lds[buf][1][c * 2048 + tid * 8]);
        }
    };

    const int arow = wr * 64 + l15;
    const int brow = wc * 64 + l15;
    #define RA(buf, f, kk) (*(const bf16x8*)((const char*)lds[buf][0] + \
        (arow + (f) * 16) * 128 + ((((kk) * 4 + l4) ^ l7) * 16)))
    #define RB(buf, j, kk) (*(const bf16x8*)((const char*)lds[buf][1] + \
        (brow + (j) * 16) * 128 + ((((kk) * 4 + l4) ^ l7) * 16)))

    f32x4 acc[4][4];
    #pragma unroll
    for (int f = 0; f < 4; ++f)
        #pragma unroll
        for (int j = 0; j < 4; ++j)
            #pragma unroll
            for (int e = 0; e < 4; ++e) acc[f][j][e] = 0.f;

    stage(0, 0);
    __syncthreads();

    for (int t = 0; t < NT; ++t) {
        const int buf = t & 1;
        if (t + 1 < NT) stage(buf ^ 1, t + 1);   // issue next-tile loads FIRST
        bf16x8 af[4][2], bfr[4][2];
        #pragma unroll
        for (int f = 0; f < 4; ++f) { af[f][0] = RA(buf, f, 0); af[f][1] = RA(buf, f, 1); }
        #pragma unroll
        for (int j = 0; j < 4; ++j) { bfr[j][0] = RB(buf, j, 0); bfr[j][1] = RB(buf, j, 1); }
        if (PRIO) __builtin_amdgcn_s_setprio(1);
        #pragma unroll
        for (int f = 0; f < 4; ++f)
            #pragma unroll
            for (int j = 0; j < 4; ++j) {
                acc[f][j] = MFMA(af[f][0], bfr[j][0], acc[f][j]);
                acc[f][j] = MFMA(af[f][1], bfr[j][1], acc[f][j]);
            }
        if (PRIO) __builtin_amdgcn_s_setprio(0);
        __syncthreads();   // drains vmcnt (stage had the whole phase to land)
    }
    #undef RA
    #undef RB

    // epilogue: C/D layout col = lane&15, row = (lane>>4)*4 + reg  [m89-verified]
    #pragma unroll
    for (int f = 0; f < 4; ++f) {
        #pragma unroll
        for (int j = 0; j < 4; ++j) {
            #pragma unroll
            for (int r = 0; r < 4; ++r) {
                int m = m0 + wr * 64 + f * 16 + l4 * 4 + r;
                int n = n0 + wc * 64 + j * 16 + l15;
                float v = acc[f][j][r];
                if (MODE == 0) {
                    if (n0 < 1024) {
                        q_out[m * 1024 + n] = (bf16)((v + bias0[n]) * QSCALE);
                    } else if (n0 < 2048) {
                        int nn = n - 1024;
                        k_out[m * 1024 + nn] = (bf16)(v + bias1[nn]);
                    } else {
                        int nn = n - 2048;
                        int hl = nn >> 7, d = nn & 127;
                        int bb = m >> 10, tt = m & 1023;
                        vt_out[((bb * 8 + hl) * 128 + d) * 1024 + tt] = (bf16)(v + bias2[nn]);
                    }
                } else {
                    f_out[m * 1024 + n] = v + bias0[n];
                }
            }
        }
    }
}

// ---------------------------------------------------------------- flash attention v5
// R18/R20 champion attn: QBLK=128 (grid 512, 4 waves x 32 q-rows), swapped
// QK^T (mfma(K,Q)) with packed-u32 P writes, un-subtracted softmax, dbuf
// single-barrier, setprio (m191 + session evidence: positive). LDS 80 KiB.
__global__ __launch_bounds__(256, 2) void attn_kernel(
    const bf16* __restrict__ qb, const bf16* __restrict__ kb,
    const bf16* __restrict__ vtb, const int* __restrict__ mask,
    bf16* __restrict__ yb)
{
    const int tid = threadIdx.x;
    const int lane = tid & 63;
    const int wid = tid >> 6;
    const int g = blockIdx.x;
    const int orig = (g & 7) * 64 + (g >> 3);   // bijective XCD swizzle (512 = 8*64)
    const int bh = orig >> 3;
    const int qt = orig & 7;
    const int b = bh >> 3;
    const int h = bh & 7;
    const int m0 = b * 1024 + qt * 128;
    const int l15 = lane & 15, l4 = lane >> 4;

    __shared__ __align__(16) char smem[81920];
    auto stageKV = [&](int bufKV, int kt) {
        char* Kb = smem + bufKV * 16384;
        char* Vb = smem + 32768 + bufKV * 16384;
        #pragma unroll
        for (int n = 0; n < 4; ++n)
            GLDS16(kb + (b * 1024 + kt + n * 16 + (tid >> 4)) * 1024 + h * 128 +
                       (((tid & 15) ^ ((tid >> 4) & 7)) * 8),
                   Kb + n * 4096 + tid * 16);
        #pragma unroll
        for (int n = 0; n < 4; ++n)
            GLDS16(vtb + (bh * 128 + n * 32 + (tid >> 3)) * 1024 + kt +
                       (((tid & 7) ^ ((tid >> 3) & 7)) * 8),
                   Vb + n * 4096 + tid * 16);
    };

    bf16x8 qf[2][4];
    #pragma unroll
    for (int i = 0; i < 2; ++i)
        #pragma unroll
        for (int kc = 0; kc < 4; ++kc)
            qf[i][kc] = *(const bf16x8*)(qb +
                (m0 + wid * 32 + i * 16 + l15) * 1024 + h * 128 + kc * 32 + l4 * 8);

    f32x4 o[2][8];
    #pragma unroll
    for (int i = 0; i < 2; ++i)
        #pragma unroll
        for (int jd = 0; jd < 8; ++jd)
            #pragma unroll
            for (int e = 0; e < 4; ++e) o[i][jd][e] = 0.f;
    float l_run[2] = {0.f, 0.f};       // per-lane, q = i*16 + l15

    stageKV(0, 0);
    __syncthreads();

    for (int t = 0; t < 16; ++t) {
        const int buf = t & 1;
        const int kt = t * 64;
        if (t + 1 < 16) stageKV(buf ^ 1, kt + 64);   // issue next K/V FIRST

        int4 mv4[4];
        #pragma unroll
        for (int j = 0; j < 4; ++j)
            mv4[j] = *(const int4*)(mask + b * 1024 + kt + j * 16 + l4 * 4);

        const char* Ks = smem + buf * 16384;
        const char* Vs = smem + 32768 + buf * 16384;

        // S^T = K Q^T (swapped): lane holds S[q=i*16+l15][k=j*16+l4*4+r]
        f32x4 s[2][4];
        #pragma unroll
        for (int i = 0; i < 2; ++i)
            #pragma unroll
            for (int j = 0; j < 4; ++j)
                #pragma unroll
                for (int e = 0; e < 4; ++e) s[i][j][e] = 0.f;
        #pragma unroll
        for (int kc = 0; kc < 4; ++kc) {
            bf16x8 kf[4];
            #pragma unroll
            for (int j = 0; j < 4; ++j)
                kf[j] = *(const bf16x8*)(Ks + (j * 16 + l15) * 256 +
                    (((kc * 4 + l4) ^ (lane & 7)) * 16));
            __builtin_amdgcn_s_setprio(1);
            #pragma unroll
            for (int i = 0; i < 2; ++i)
                #pragma unroll
                for (int j = 0; j < 4; ++j)
                    s[i][j] = MFMA(kf[j], qf[i][kc], s[i][j]);
            __builtin_amdgcn_s_setprio(0);
        }

        // un-subtracted softmax: p = exp2(s) (mask -> 0); per-lane partials
        #pragma unroll
        for (int i = 0; i < 2; ++i)
            #pragma unroll
            for (int j = 0; j < 4; ++j) {
                s[i][j][0] = mv4[j].x ? __builtin_amdgcn_exp2f(s[i][j][0]) : 0.f;
                s[i][j][1] = mv4[j].y ? __builtin_amdgcn_exp2f(s[i][j][1]) : 0.f;
                s[i][j][2] = mv4[j].z ? __builtin_amdgcn_exp2f(s[i][j][2]) : 0.f;
                s[i][j][3] = mv4[j].w ? __builtin_amdgcn_exp2f(s[i][j][3]) : 0.f;
                l_run[i] += s[i][j][0] + s[i][j][1] + s[i][j][2] + s[i][j][3];
            }

        // P -> per-wave LDS [32 q][32 u32], packed pairs, swizzled chunk^(q&7)
        #pragma unroll
        for (int i = 0; i < 2; ++i) {
            char* pw = smem + 65536 + wid * 4096 + (i * 16 + l15) * 128;
            #pragma unroll
            for (int j = 0; j < 4; ++j) {
                char* pcq = pw + (((j * 2 + (l4 >> 1)) ^ (l15 & 7)) * 16) +
                            ((l4 & 1) * 2) * 4;
                *(unsigned*)(pcq)     = pack2(s[i][j][0], s[i][j][1]);
                *(unsigned*)(pcq + 4) = pack2(s[i][j][2], s[i][j][3]);
            }
        }

        // O += P V
        #pragma unroll
        for (int k2 = 0; k2 < 2; ++k2) {
            bf16x8 pa[2];
            #pragma unroll
            for (int i = 0; i < 2; ++i)
                pa[i] = *(const bf16x8*)(smem + 65536 + wid * 4096 +
                    (i * 16 + l15) * 128 + (((k2 * 4 + l4) ^ (l15 & 7)) * 16));
            __builtin_amdgcn_s_setprio(1);
            #pragma unroll
            for (int jd = 0; jd < 8; ++jd) {
                bf16x8 vf = *(const bf16x8*)(Vs + (jd * 16 + l15) * 128 +
                    (((k2 * 4 + l4) ^ (l15 & 7)) * 16));
                o[0][jd] = MFMA(pa[0], vf, o[0][jd]);
                o[1][jd] = MFMA(pa[1], vf, o[1][jd]);
            }
            __builtin_amdgcn_s_setprio(0);
        }
        __syncthreads();
    }

    // epilogue: reduce l over l4 groups, transpose to O-layout q via LDS scratch
    #pragma unroll
    for (int i = 0; i < 2; ++i) {
        l_run[i] += __shfl_xor(l_run[i], 16);
        l_run[i] += __shfl_xor(l_run[i], 32);
    }
    float* sc = (float*)(smem + 65536 + wid * 4096);   // reuse dead P region
    if (l4 == 0) { sc[l15] = l_run[0]; sc[16 + l15] = l_run[1]; }
    __syncthreads();
    #pragma unroll
    for (int i = 0; i < 2; ++i) {
        float inv[4];
        #pragma unroll
        for (int r = 0; r < 4; ++r)
            inv[r] = 1.0f / fmaxf(sc[i * 16 + l4 * 4 + r], 1e-30f);
        #pragma unroll
        for (int jd = 0; jd < 8; ++jd)
            #pragma unroll
            for (int r = 0; r < 4; ++r)
                yb[(m0 + wid * 32 + i * 16 + l4 * 4 + r) * 1024 +
                   h * 128 + jd * 16 + l15] = (bf16)(o[i][jd][r] * inv[r]);
    }
}

// ---------------------------------------------------------------- launch
extern "C" void kernel_launch(void* const* d_in, const int* in_sizes, int n_in,
                              void* d_out, int out_size, void* d_ws, size_t ws_size,
                              hipStream_t stream)
{
    (void)in_sizes; (void)n_in; (void)out_size; (void)ws_size;
    const float* x  = (const float*)d_in[0];
    const int* mask = (const int*)d_in[1];
    const float* Wq = (const float*)d_in[2];
    const float* bq = (const float*)d_in[3];
    const float* Wk = (const float*)d_in[4];
    const float* bk = (const float*)d_in[5];
    const float* Wv = (const float*)d_in[6];
    const float* bv = (const float*)d_in[7];
    const float* Wp = (const float*)d_in[8];
    const float* bp = (const float*)d_in[9];
    float* out = (float*)d_out;

    char* ws = (char*)d_ws;
    bf16* xb    = (bf16*)(ws);                      // 16 MB  x bf16 (8192 x 1024)
    bf16* wqkvb = (bf16*)(ws + (16u << 20));        //  6 MB  [Wq;Wk;Wv]
    bf16* wpb   = (bf16*)(ws + (22u << 20));        //  2 MB  Wp
    bf16* qbuf  = (bf16*)(ws + (24u << 20));        // 16 MB  q (scaled)
    bf16* kbuf  = (bf16*)(ws + (40u << 20));        // 16 MB  k
    bf16* vtb   = (bf16*)(ws + (56u << 20));        // 16 MB  v^T per (b,h)
    bf16* ybuf  = (bf16*)(ws + (72u << 20));        // 16 MB  attention out

    convert_kernel<<<6144, 256, 0, stream>>>(x, Wq, Wk, Wv, Wp, xb, wqkvb, wpb);
    gemm2<0, 24, 1><<<1536, 256, 0, stream>>>(xb, wqkvb, bq, bk, bv,
                                              qbuf, kbuf, vtb, nullptr);
    attn_kernel<<<512, 256, 0, stream>>>(qbuf, kbuf, vtb, mask, ybuf);
    gemm2<1, 8, 0><<<512, 256, 0, stream>>>(ybuf, wpb, bp, nullptr, nullptr,
                                            nullptr, nullptr, nullptr, out);
}